// Round 7
// baseline (342.259 us; speedup 1.0000x reference)
//
#include <hip/hip_runtime.h>
#include <hip/hip_fp16.h>
#include <stdint.h>

// ---------------- problem constants ----------------
#define NODES 50000
#define F_IN 128
#define F_H1 256
#define F_H2 256
#define F_OUT 64
#define NR 8          // node ranges (== XCD count; blockIdx%8 round-robins XCDs)
#define NSLICE 128    // edge slices per range

using f32x4    = __attribute__((ext_vector_type(4))) float;
using f16x8    = __attribute__((ext_vector_type(8))) _Float16;   // 8 fp16 in 4 VGPRs
using ushort8v = __attribute__((ext_vector_type(8))) unsigned short;

// ---------------- degree / CSR build ----------------
__global__ void k_init(int* deg_out, int* deg_in, int* cursor, int n) {
  int i = blockIdx.x * blockDim.x + threadIdx.x;
  if (i < n) { deg_out[i] = 1; deg_in[i] = 1; cursor[i] = 0; }  // self-loop counts as 1
}

// XCD-localized degree count: block (range r = b&7, slice s = b>>3) only
// touches counters in its node range -> atomic lines stay in one XCD's L2.
__global__ __launch_bounds__(256) void k_count_p(
    const int* __restrict__ src, const int* __restrict__ dst,
    int* __restrict__ deg_out, int* __restrict__ deg_in, int e, int rangeSize) {
  const int r = blockIdx.x & (NR - 1);
  const int s = blockIdx.x >> 3;
  const int lo = r * rangeSize;
  const int hi = lo + rangeSize;
  const int per = (e + NSLICE - 1) / NSLICE;
  const int beg = s * per;
  const int end = min(e, beg + per);
  for (int i = beg + (int)threadIdx.x; i < end; i += 256) {
    int a = src[i];
    if (a >= lo && a < hi) atomicAdd(&deg_out[a], 1);
    int b = dst[i];
    if (b >= lo && b < hi) atomicAdd(&deg_in[b], 1);
  }
}

__global__ void k_norm(const int* __restrict__ deg_out, const int* __restrict__ deg_in,
                       float* ns, float* nd, int n) {
  int i = blockIdx.x * blockDim.x + threadIdx.x;
  if (i < n) {
    ns[i] = rsqrtf((float)deg_out[i]);
    nd[i] = rsqrtf((float)deg_in[i]);
  }
}

// ---------------- parallel 3-phase exclusive scan over (deg_in - 1) ----------------
__global__ __launch_bounds__(256) void k_scan1(const int* __restrict__ deg_in,
                                               int* __restrict__ psum, int n) {
  int i = blockIdx.x * 256 + threadIdx.x;
  int v = (i < n) ? deg_in[i] - 1 : 0;
#pragma unroll
  for (int o = 1; o < 64; o <<= 1) v += __shfl_xor(v, o);
  __shared__ int ws[4];
  if ((threadIdx.x & 63) == 0) ws[threadIdx.x >> 6] = v;
  __syncthreads();
  if (threadIdx.x == 0) psum[blockIdx.x] = ws[0] + ws[1] + ws[2] + ws[3];
}

__global__ __launch_bounds__(256) void k_scan2(int* __restrict__ psum, int nb) {
  __shared__ int s[256];
  int t = threadIdx.x;
  int v = (t < nb) ? psum[t] : 0;
  s[t] = v;
  __syncthreads();
  for (int o = 1; o < 256; o <<= 1) {
    int u = (t >= o) ? s[t - o] : 0;
    __syncthreads();
    s[t] += u;
    __syncthreads();
  }
  if (t < nb) psum[t] = s[t] - v;   // exclusive
}

__global__ __launch_bounds__(256) void k_scan3(const int* __restrict__ deg_in,
                                               const int* __restrict__ psum,
                                               int* __restrict__ row_ptr, int n) {
  int i = blockIdx.x * 256 + threadIdx.x;
  int lane = threadIdx.x & 63;
  int w = threadIdx.x >> 6;
  int v = (i < n) ? deg_in[i] - 1 : 0;
  int x = v;
#pragma unroll
  for (int o = 1; o < 64; o <<= 1) {
    int u = __shfl_up(x, o);
    if (lane >= o) x += u;
  }
  __shared__ int wsum[4];
  if (lane == 63) wsum[w] = x;
  __syncthreads();
  int woff = 0;
#pragma unroll
  for (int j = 0; j < 4; ++j)
    if (j < w) woff += wsum[j];
  int excl = x - v + woff + psum[blockIdx.x];
  if (i < n) row_ptr[i] = excl;
  if (i == n - 1) row_ptr[n] = excl + v;
}

// XCD-localized CSR scatter (partition by dst range).
__global__ __launch_bounds__(256) void k_scatter_p(
    const int* __restrict__ src, const int* __restrict__ dst,
    const int* __restrict__ row_ptr, int* __restrict__ cursor,
    int* __restrict__ csr_src, int e, int rangeSize) {
  const int r = blockIdx.x & (NR - 1);
  const int s = blockIdx.x >> 3;
  const int lo = r * rangeSize;
  const int hi = lo + rangeSize;
  const int per = (e + NSLICE - 1) / NSLICE;
  const int beg = s * per;
  const int end = min(e, beg + per);
  for (int i = beg + (int)threadIdx.x; i < end; i += 256) {
    int d = dst[i];
    if (d >= lo && d < hi) {
      int pos = row_ptr[d] + atomicAdd(&cursor[d], 1);
      csr_src[pos] = src[i];
    }
  }
}

// ---------------- feats prescale -> fp16: Y = fp16(ns[row] * X), X:[n][128] ----------------
__global__ void k_prescale_h(const float* __restrict__ X, const float* __restrict__ ns,
                             __half* __restrict__ Y, int total4) {
  int i = blockIdx.x * blockDim.x + threadIdx.x;
  if (i < total4) {
    int row = i >> 5;                       // 32 float4 per 128-col row
    float s = ns[row];
    float4 v = reinterpret_cast<const float4*>(X)[i];
    __half2 h0 = __floats2half2_rn(v.x * s, v.y * s);
    __half2 h1 = __floats2half2_rn(v.z * s, v.w * s);
    union { struct { __half2 a, b; } h; uint2 u; } o;
    o.h.a = h0; o.h.b = h1;
    reinterpret_cast<uint2*>(Y)[i] = o.u;
  }
}

// ---------------- weight prep: W[K][NOUT] f32 -> Wt [NOUT][K] fp16 ----------------
__global__ void k_wprep_h(const float* __restrict__ W, __half* __restrict__ Wt,
                          int K, int NOUT) {
  int i = blockIdx.x * blockDim.x + threadIdx.x;
  if (i < K * NOUT) {
    int k = i / NOUT, n = i % NOUT;
    Wt[(size_t)n * K + k] = __float2half_rn(W[i]);
  }
}

// ---------------- fp16 gather helpers ----------------
template <int HPL> struct raw_t_sel;
template <> struct raw_t_sel<1> { using type = unsigned short; };
template <> struct raw_t_sel<2> { using type = unsigned int; };
template <> struct raw_t_sel<4> { using type = uint2; };

template <int HPL>
__device__ __forceinline__ typename raw_t_sel<HPL>::type graw(const __half* p) {
  return *reinterpret_cast<const typename raw_t_sel<HPL>::type*>(p);
}
template <int HPL>
__device__ __forceinline__ void raw_acc(float* acc, typename raw_t_sel<HPL>::type r) {
  if constexpr (HPL == 4) {
    union { unsigned u; __half2 h; } a, b;
    a.u = r.x; b.u = r.y;
    float2 f0 = __half22float2(a.h), f1 = __half22float2(b.h);
    acc[0] += f0.x; acc[1] += f0.y; acc[2] += f1.x; acc[3] += f1.y;
  } else if constexpr (HPL == 2) {
    union { unsigned u; __half2 h; } a; a.u = r;
    float2 f0 = __half22float2(a.h);
    acc[0] += f0.x; acc[1] += f0.y;
  } else {
    union { unsigned short u; __half h; } a; a.u = r;
    acc[0] += __half2float(a.h);
  }
}

// ---------------- SpMM (fp16 source): Y[v] = nd[v]*(X[v] + sum_{u->v} X[u]) (+bias)
// WPN waves per node (disjoint feature parts); HPL halves per lane. OHALF: fp16 out.
template <int D, int WPN, bool BIAS, bool OHALF>
__global__ __launch_bounds__(256) void k_spmm_h(
    const __half* __restrict__ X, const int* __restrict__ row_ptr,
    const int* __restrict__ csr_src, const float* __restrict__ nd,
    const float* __restrict__ bias, void* __restrict__ Y, int n) {
  constexpr int HPL = D / (64 * WPN);
  static_assert(HPL >= 1 && HPL <= 4, "bad HPL");
  using raw_t = typename raw_t_sel<HPL>::type;
  const int gw = (blockIdx.x * blockDim.x + threadIdx.x) >> 6;
  const int lane = threadIdx.x & 63;
  const int v = (WPN == 2) ? (gw >> 1) : gw;
  const int part = (WPN == 2) ? (gw & 1) : 0;
  if (v >= n) return;
  const int off = part * 64 * HPL + lane * HPL;
  const __half* __restrict__ Xo = X + off;

  float acc[HPL] = {};
  raw_acc<HPL>(acc, graw<HPL>(Xo + (size_t)v * D));   // self term

  const int end = row_ptr[v + 1];
  int e = row_ptr[v];
  for (; e + 4 <= end; e += 4) {
    int u0 = csr_src[e + 0], u1 = csr_src[e + 1];
    int u2 = csr_src[e + 2], u3 = csr_src[e + 3];
    raw_t r0 = graw<HPL>(Xo + (size_t)u0 * D);
    raw_t r1 = graw<HPL>(Xo + (size_t)u1 * D);
    raw_t r2 = graw<HPL>(Xo + (size_t)u2 * D);
    raw_t r3 = graw<HPL>(Xo + (size_t)u3 * D);
    raw_acc<HPL>(acc, r0); raw_acc<HPL>(acc, r1);
    raw_acc<HPL>(acc, r2); raw_acc<HPL>(acc, r3);
  }
  for (; e < end; ++e) {
    raw_acc<HPL>(acc, graw<HPL>(Xo + (size_t)csr_src[e] * D));
  }

  const float sc = nd[v];
  float o[HPL];
#pragma unroll
  for (int i = 0; i < HPL; ++i) {
    o[i] = sc * acc[i];
    if (BIAS) o[i] += bias[off + i];
  }

  if constexpr (OHALF) {
    __half* yp = reinterpret_cast<__half*>(Y) + (size_t)v * D + off;
    if constexpr (HPL == 4) {
      union { struct { __half2 a, b; } h; uint2 u; } pk;
      pk.h.a = __floats2half2_rn(o[0], o[1]);
      pk.h.b = __floats2half2_rn(o[2], o[3]);
      *reinterpret_cast<uint2*>(yp) = pk.u;
    } else if constexpr (HPL == 2) {
      *reinterpret_cast<__half2*>(yp) = __floats2half2_rn(o[0], o[1]);
    } else {
      *yp = __float2half_rn(o[0]);
    }
  } else {
    float* yp = reinterpret_cast<float*>(Y) + (size_t)v * D + off;
    if constexpr (HPL == 4) *reinterpret_cast<float4*>(yp) = make_float4(o[0], o[1], o[2], o[3]);
    else if constexpr (HPL == 2) *reinterpret_cast<float2*>(yp) = make_float2(o[0], o[1]);
    else *yp = o[0];
  }
}

// ---------------- pure-fp16 MFMA GEMM ----------------
// C[M][NOUT] = op( A[M][K] @ W[K][NOUT] (+bias) ) [* ns[row] if NSOUT]
// A fp16 row-major; Wt fp16 pre-transposed [NOUT][K]; f32 accumulate via
// mfma_f32_16x16x32_f16.  OHALF: C written as fp16, else f32.
template <int K, int NOUT, int BM, int WM, int WN, int MF, int NF,
          bool RELU, bool BIAS, bool NSOUT, bool OHALF>
__global__ __launch_bounds__(256) void k_gemm_h(
    const __half* __restrict__ A, const __half* __restrict__ Wt,
    const float* __restrict__ bias, const float* __restrict__ ns,
    void* __restrict__ C, int M) {
  constexpr int BN = WN * NF * 16;
  static_assert(BM == WM * MF * 16, "BM mismatch");
  static_assert(BN == NOUT, "BN must equal NOUT");
  constexpr int LDP = 40;  // 80B row stride -> bank stride 20 -> <=2-way (free), 16B aligned

  __shared__ __half As[BM][LDP];
  __shared__ __half Ws[BN][LDP];

  const int tid = threadIdx.x;
  const int bm = blockIdx.x * BM;
  const int lane = tid & 63;
  const int wave = tid >> 6;
  const int wmi = wave / WN;
  const int wni = wave % WN;
  const int rl = lane & 15;
  const int kg = lane >> 4;       // 0..3
  const int kb = kg * 8;

  f32x4 acc[MF][NF];
#pragma unroll
  for (int m = 0; m < MF; ++m)
#pragma unroll
    for (int n = 0; n < NF; ++n) acc[m][n] = (f32x4){0.f, 0.f, 0.f, 0.f};

  for (int kk = 0; kk < K; kk += 32) {
    // ---- stage A tile (BM x 32 fp16): ushort8 per slot ----
#pragma unroll
    for (int s0 = 0; s0 < BM * 4; s0 += 256) {
      int s = s0 + tid;
      int r = s >> 2, c8 = (s & 3) << 3;
      int grow = bm + r;
      ushort8v v = (ushort8v){0, 0, 0, 0, 0, 0, 0, 0};
      if (grow < M)
        v = *reinterpret_cast<const ushort8v*>(A + (size_t)grow * K + kk + c8);
      *reinterpret_cast<ushort8v*>(&As[r][c8]) = v;
    }
    // ---- stage W tile (BN cols x 32 k) ----
#pragma unroll
    for (int s0 = 0; s0 < BN * 4; s0 += 256) {
      int s = s0 + tid;
      int nn = s >> 2, k8 = (s & 3) << 3;
      *reinterpret_cast<ushort8v*>(&Ws[nn][k8]) =
          *reinterpret_cast<const ushort8v*>(Wt + (size_t)nn * K + kk + k8);
    }
    __syncthreads();

    f16x8 af[MF], bf[NF];
#pragma unroll
    for (int m = 0; m < MF; ++m) {
      const int r = wmi * MF * 16 + m * 16 + rl;
      af[m] = *reinterpret_cast<const f16x8*>(&As[r][kb]);
    }
#pragma unroll
    for (int n = 0; n < NF; ++n) {
      const int c = wni * NF * 16 + n * 16 + rl;
      bf[n] = *reinterpret_cast<const f16x8*>(&Ws[c][kb]);
    }
#pragma unroll
    for (int m = 0; m < MF; ++m)
#pragma unroll
      for (int n = 0; n < NF; ++n)
        acc[m][n] = __builtin_amdgcn_mfma_f32_16x16x32_f16(af[m], bf[n], acc[m][n], 0, 0, 0);
    __syncthreads();
  }

  // ---- epilogue ----
#pragma unroll
  for (int m = 0; m < MF; ++m) {
#pragma unroll
    for (int n = 0; n < NF; ++n) {
      const int col = wni * NF * 16 + n * 16 + rl;
      const float bb = BIAS ? bias[col] : 0.f;
      const int rowbase = bm + wmi * MF * 16 + m * 16 + kg * 4;
#pragma unroll
      for (int i = 0; i < 4; ++i) {
        int grow = rowbase + i;
        if (grow < M) {
          float val = acc[m][n][i] + bb;
          if (RELU) val = fmaxf(val, 0.f);
          if (NSOUT) val *= ns[grow];
          if constexpr (OHALF)
            reinterpret_cast<__half*>(C)[(size_t)grow * NOUT + col] = __float2half_rn(val);
          else
            reinterpret_cast<float*>(C)[(size_t)grow * NOUT + col] = val;
        }
      }
    }
  }
}

// ---------------- launch ----------------
extern "C" void kernel_launch(void* const* d_in, const int* in_sizes, int n_in,
                              void* d_out, int out_size, void* d_ws, size_t ws_size,
                              hipStream_t stream) {
  const float* feats = (const float*)d_in[0];
  const float* W1 = (const float*)d_in[1];
  const float* b1 = (const float*)d_in[2];
  const float* W2 = (const float*)d_in[3];
  const float* b2 = (const float*)d_in[4];
  const float* W3 = (const float*)d_in[5];
  const float* b3 = (const float*)d_in[6];
  const int* src = (const int*)d_in[7];
  const int* dst = (const int*)d_in[8];
  float* out = (float*)d_out;
  const int N = NODES;
  const int E = in_sizes[7];
  const int NB = (N + 255) / 256;          // scan blocks (196 <= 256)
  const int RANGE = (N + NR - 1) / NR;     // 6250 nodes per XCD range

  char* ws = (char*)d_ws;
  size_t off = 0;
  auto alloc = [&](size_t bytes) -> void* {
    void* p = ws + off;
    off += (bytes + 255) & ~(size_t)255;
    return p;
  };
  __half* w0h = (__half*)alloc((size_t)N * 256 * sizeof(__half));
  __half* w1r = (__half*)alloc((size_t)N * 256 * sizeof(__half));
  __half* w2r = (__half*)alloc((size_t)N * 256 * sizeof(__half));
  int* deg_out = (int*)alloc((size_t)N * sizeof(int));
  int* deg_in = (int*)alloc((size_t)N * sizeof(int));
  int* cursor = (int*)alloc((size_t)N * sizeof(int));
  float* ns = (float*)alloc((size_t)N * sizeof(float));
  float* nd = (float*)alloc((size_t)N * sizeof(float));
  int* row_ptr = (int*)alloc((size_t)(N + 1) * sizeof(int));
  int* csr_src = (int*)alloc((size_t)E * sizeof(int));
  int* psum = (int*)alloc((size_t)NB * sizeof(int));
  __half* wt1 = (__half*)alloc((size_t)F_IN * F_H1 * sizeof(__half));
  __half* wt2 = (__half*)alloc((size_t)F_H1 * F_H2 * sizeof(__half));
  __half* wt3 = (__half*)alloc((size_t)F_H2 * F_OUT * sizeof(__half));
  (void)ws_size; (void)n_in; (void)out_size;

  // ---- weight transpose -> fp16 (tiny) ----
  hipLaunchKernelGGL(k_wprep_h, dim3((F_IN * F_H1 + 255) / 256), dim3(256), 0, stream,
                     W1, wt1, F_IN, F_H1);
  hipLaunchKernelGGL(k_wprep_h, dim3((F_H1 * F_H2 + 255) / 256), dim3(256), 0, stream,
                     W2, wt2, F_H1, F_H2);
  hipLaunchKernelGGL(k_wprep_h, dim3((F_H2 * F_OUT + 255) / 256), dim3(256), 0, stream,
                     W3, wt3, F_H2, F_OUT);

  // ---- graph preprocessing (XCD-localized atomics) ----
  hipLaunchKernelGGL(k_init, dim3((N + 255) / 256), dim3(256), 0, stream,
                     deg_out, deg_in, cursor, N);
  hipLaunchKernelGGL(k_count_p, dim3(NSLICE * NR), dim3(256), 0, stream,
                     src, dst, deg_out, deg_in, E, RANGE);
  hipLaunchKernelGGL(k_norm, dim3((N + 255) / 256), dim3(256), 0, stream,
                     deg_out, deg_in, ns, nd, N);
  hipLaunchKernelGGL(k_scan1, dim3(NB), dim3(256), 0, stream, deg_in, psum, N);
  hipLaunchKernelGGL(k_scan2, dim3(1), dim3(256), 0, stream, psum, NB);
  hipLaunchKernelGGL(k_scan3, dim3(NB), dim3(256), 0, stream, deg_in, psum, row_ptr, N);
  hipLaunchKernelGGL(k_scatter_p, dim3(NSLICE * NR), dim3(256), 0, stream,
                     src, dst, row_ptr, cursor, csr_src, E, RANGE);

  // ---- prescale feats by ns -> fp16 ----
  hipLaunchKernelGGL(k_prescale_h, dim3((N * 32 + 255) / 256), dim3(256), 0, stream,
                     feats, ns, w2r, N * 32);

  auto grid_w = [](int waves) { return dim3((waves + 3) / 4); };  // 4 waves/block

  // ---- layer 1: SpMM(d=128, 1 wave/node) -> fp16; GEMM 128->256 (+b1, relu, *ns) -> fp16
  hipLaunchKernelGGL((k_spmm_h<128, 1, false, true>), grid_w(N), dim3(256), 0, stream,
                     w2r, row_ptr, csr_src, nd, nullptr, w1r, N);
  hipLaunchKernelGGL((k_gemm_h<128, 256, 64, 1, 4, 4, 4, true, true, true, true>),
                     dim3((N + 63) / 64), dim3(256), 0, stream,
                     w1r, wt1, b1, ns, w2r, N);

  // ---- layer 2: SpMM(d=256, 1 wave/node) -> fp16; GEMM 256->256 (+b2, relu, *ns) -> fp16
  hipLaunchKernelGGL((k_spmm_h<256, 1, false, true>), grid_w(N), dim3(256), 0, stream,
                     w2r, row_ptr, csr_src, nd, nullptr, w0h, N);
  hipLaunchKernelGGL((k_gemm_h<256, 256, 64, 1, 4, 4, 4, true, true, true, true>),
                     dim3((N + 63) / 64), dim3(256), 0, stream,
                     w0h, wt2, b2, ns, w1r, N);

  // ---- layer 3: GEMM 256->64 (no act) -> fp16; SpMM(d=64) +b3 -> out f32
  hipLaunchKernelGGL((k_gemm_h<256, 64, 128, 4, 1, 2, 4, false, false, false, true>),
                     dim3((N + 127) / 128), dim3(256), 0, stream,
                     w1r, wt3, nullptr, nullptr, w2r, N);
  hipLaunchKernelGGL((k_spmm_h<64, 1, true, false>), grid_w(N), dim3(256), 0, stream,
                     w2r, row_ptr, csr_src, nd, b3, out, N);
}

// Round 8
// 288.698 us; speedup vs baseline: 1.1855x; 1.1855x over previous
//
#include <hip/hip_runtime.h>
#include <hip/hip_fp16.h>
#include <stdint.h>

// ---------------- problem constants ----------------
#define NODES 50000
#define F_IN 128
#define F_H1 256
#define F_H2 256
#define F_OUT 64
#define SLICES 64            // edge slices for hist/scatter
#define NPACK (NODES / 2)    // packed ushort-pair bins (25000)
#define HPACK (NPACK / 2)    // bins per node-half block (12500, 50 KB LDS)

using f32x4    = __attribute__((ext_vector_type(4))) float;
using f16x8    = __attribute__((ext_vector_type(8))) _Float16;   // 8 fp16 in 4 VGPRs
using ushort8v = __attribute__((ext_vector_type(8))) unsigned short;

// ---------------- atomic-free degree/CSR machinery ----------------
// k_hist: block (s = b>>1, r = b&1) histograms edge-slice s for node half r
// into packed-ushort LDS bins; writes partial rows for src (out-deg) and dst (in-deg).
__global__ __launch_bounds__(512) void k_hist(
    const int* __restrict__ src, const int* __restrict__ dst,
    unsigned* __restrict__ p_out, unsigned* __restrict__ p_in, int e) {
  __shared__ unsigned bins[HPACK];
  const int s = blockIdx.x >> 1;
  const int r = blockIdx.x & 1;
  const int nlo = r * (NODES / 2);
  const int nhi = nlo + NODES / 2;
  const int plo = r * HPACK;
  const int per = (e + SLICES - 1) / SLICES;
  const int beg = s * per;
  const int end = min(e, beg + per);

  // ---- src pass (out-degree) ----
  for (int j = threadIdx.x; j < HPACK; j += 512) bins[j] = 0;
  __syncthreads();
  for (int i = beg + (int)threadIdx.x; i < end; i += 512) {
    int a = src[i];
    if (a >= nlo && a < nhi)
      atomicAdd(&bins[(a >> 1) - plo], 1u << ((a & 1) << 4));
  }
  __syncthreads();
  for (int j = threadIdx.x; j < HPACK; j += 512)
    p_out[(size_t)s * NPACK + plo + j] = bins[j];
  __syncthreads();

  // ---- dst pass (in-degree) ----
  for (int j = threadIdx.x; j < HPACK; j += 512) bins[j] = 0;
  __syncthreads();
  for (int i = beg + (int)threadIdx.x; i < end; i += 512) {
    int d = dst[i];
    if (d >= nlo && d < nhi)
      atomicAdd(&bins[(d >> 1) - plo], 1u << ((d & 1) << 4));
  }
  __syncthreads();
  for (int j = threadIdx.x; j < HPACK; j += 512)
    p_in[(size_t)s * NPACK + plo + j] = bins[j];
}

// k_degnorm: reduce partials -> degrees (+1 self-loop), fused rsqrt norms,
// and write per-slice exclusive prefix (scatter bases) for the dst direction.
__global__ __launch_bounds__(256) void k_degnorm(
    const unsigned* __restrict__ p_out, const unsigned* __restrict__ p_in,
    unsigned* __restrict__ base_in, int* __restrict__ deg_in,
    float* __restrict__ ns, float* __restrict__ nd) {
  int p = blockIdx.x * 256 + threadIdx.x;
  if (p >= NPACK) return;
  unsigned so = 0, si = 0;
#pragma unroll 4
  for (int s = 0; s < SLICES; ++s) {
    so += p_out[(size_t)s * NPACK + p];
    unsigned vi = p_in[(size_t)s * NPACK + p];
    base_in[(size_t)s * NPACK + p] = si;   // exclusive prefix across slices
    si += vi;
  }
  int o0 = (int)(so & 0xFFFFu) + 1, o1 = (int)(so >> 16) + 1;   // +1 self-loop
  int i0 = (int)(si & 0xFFFFu) + 1, i1 = (int)(si >> 16) + 1;
  int n0 = p * 2, n1 = n0 + 1;
  deg_in[n0] = i0; deg_in[n1] = i1;
  ns[n0] = rsqrtf((float)o0); ns[n1] = rsqrtf((float)o1);
  nd[n0] = rsqrtf((float)i0); nd[n1] = rsqrtf((float)i1);
}

// ---------------- parallel 3-phase exclusive scan over (deg_in - 1) ----------------
__global__ __launch_bounds__(256) void k_scan1(const int* __restrict__ deg_in,
                                               int* __restrict__ psum, int n) {
  int i = blockIdx.x * 256 + threadIdx.x;
  int v = (i < n) ? deg_in[i] - 1 : 0;
#pragma unroll
  for (int o = 1; o < 64; o <<= 1) v += __shfl_xor(v, o);
  __shared__ int ws[4];
  if ((threadIdx.x & 63) == 0) ws[threadIdx.x >> 6] = v;
  __syncthreads();
  if (threadIdx.x == 0) psum[blockIdx.x] = ws[0] + ws[1] + ws[2] + ws[3];
}

__global__ __launch_bounds__(256) void k_scan2(int* __restrict__ psum, int nb) {
  __shared__ int s[256];
  int t = threadIdx.x;
  int v = (t < nb) ? psum[t] : 0;
  s[t] = v;
  __syncthreads();
  for (int o = 1; o < 256; o <<= 1) {
    int u = (t >= o) ? s[t - o] : 0;
    __syncthreads();
    s[t] += u;
    __syncthreads();
  }
  if (t < nb) psum[t] = s[t] - v;   // exclusive
}

__global__ __launch_bounds__(256) void k_scan3(const int* __restrict__ deg_in,
                                               const int* __restrict__ psum,
                                               int* __restrict__ row_ptr, int n) {
  int i = blockIdx.x * 256 + threadIdx.x;
  int lane = threadIdx.x & 63;
  int w = threadIdx.x >> 6;
  int v = (i < n) ? deg_in[i] - 1 : 0;
  int x = v;
#pragma unroll
  for (int o = 1; o < 64; o <<= 1) {
    int u = __shfl_up(x, o);
    if (lane >= o) x += u;
  }
  __shared__ int wsum[4];
  if (lane == 63) wsum[w] = x;
  __syncthreads();
  int woff = 0;
#pragma unroll
  for (int j = 0; j < 4; ++j)
    if (j < w) woff += wsum[j];
  int excl = x - v + woff + psum[blockIdx.x];
  if (i < n) row_ptr[i] = excl;
  if (i == n - 1) row_ptr[n] = excl + v;
}

// k_scatter2: counting-sort scatter, zero global atomics. Same (s,r) mapping
// as k_hist; LDS cursors seeded from base_in; LDS atomic gives in-row slot.
__global__ __launch_bounds__(512) void k_scatter2(
    const int* __restrict__ src, const int* __restrict__ dst,
    const int* __restrict__ row_ptr, const unsigned* __restrict__ base_in,
    int* __restrict__ csr_src, int e) {
  __shared__ unsigned cur[HPACK];
  const int s = blockIdx.x >> 1;
  const int r = blockIdx.x & 1;
  const int nlo = r * (NODES / 2);
  const int nhi = nlo + NODES / 2;
  const int plo = r * HPACK;
  const int per = (e + SLICES - 1) / SLICES;
  const int beg = s * per;
  const int end = min(e, beg + per);
  for (int j = threadIdx.x; j < HPACK; j += 512)
    cur[j] = base_in[(size_t)s * NPACK + plo + j];
  __syncthreads();
  for (int i = beg + (int)threadIdx.x; i < end; i += 512) {
    int d = dst[i];
    if (d >= nlo && d < nhi) {
      int sh = (d & 1) << 4;
      unsigned old = atomicAdd(&cur[(d >> 1) - plo], 1u << sh);
      int local = (int)((old >> sh) & 0xFFFFu);
      csr_src[row_ptr[d] + local] = src[i];
    }
  }
}

// ---------------- feats prescale -> fp16: Y = fp16(ns[row] * X), X:[n][128] ----------------
__global__ void k_prescale_h(const float* __restrict__ X, const float* __restrict__ ns,
                             __half* __restrict__ Y, int total4) {
  int i = blockIdx.x * blockDim.x + threadIdx.x;
  if (i < total4) {
    int row = i >> 5;                       // 32 float4 per 128-col row
    float s = ns[row];
    float4 v = reinterpret_cast<const float4*>(X)[i];
    __half2 h0 = __floats2half2_rn(v.x * s, v.y * s);
    __half2 h1 = __floats2half2_rn(v.z * s, v.w * s);
    union { struct { __half2 a, b; } h; uint2 u; } o;
    o.h.a = h0; o.h.b = h1;
    reinterpret_cast<uint2*>(Y)[i] = o.u;
  }
}

// ---------------- weight prep: W[K][NOUT] f32 -> Wt [NOUT][K] fp16 ----------------
__global__ void k_wprep_h(const float* __restrict__ W, __half* __restrict__ Wt,
                          int K, int NOUT) {
  int i = blockIdx.x * blockDim.x + threadIdx.x;
  if (i < K * NOUT) {
    int k = i / NOUT, n = i % NOUT;
    Wt[(size_t)n * K + k] = __float2half_rn(W[i]);
  }
}

// ---------------- fp16 gather helpers ----------------
template <int HPL> struct raw_t_sel;
template <> struct raw_t_sel<2> { using type = unsigned int; };
template <> struct raw_t_sel<4> { using type = uint2; };
template <> struct raw_t_sel<8> { using type = uint4; };

template <int HPL>
__device__ __forceinline__ typename raw_t_sel<HPL>::type graw(const __half* p) {
  return *reinterpret_cast<const typename raw_t_sel<HPL>::type*>(p);
}
__device__ __forceinline__ void acc_u32(float* acc, unsigned u) {
  union { unsigned u; __half2 h; } a; a.u = u;
  float2 f = __half22float2(a.h);
  acc[0] += f.x; acc[1] += f.y;
}
template <int HPL>
__device__ __forceinline__ void raw_acc(float* acc, typename raw_t_sel<HPL>::type r) {
  if constexpr (HPL == 8) {
    acc_u32(acc + 0, r.x); acc_u32(acc + 2, r.y);
    acc_u32(acc + 4, r.z); acc_u32(acc + 6, r.w);
  } else if constexpr (HPL == 4) {
    acc_u32(acc + 0, r.x); acc_u32(acc + 2, r.y);
  } else {
    acc_u32(acc, r);
  }
}

// ---------------- SpMM (fp16 source): Y[v] = nd[v]*(X[v] + sum_{u->v} X[u]) (+bias)
// EPI edges per wave-iteration: lane = (sub-edge, feature-slot); butterfly
// shfl_xor combine at the end. OHALF: fp16 out, else f32.
template <int D, int EPI, bool BIAS, bool OHALF>
__global__ __launch_bounds__(256) void k_spmm_h(
    const __half* __restrict__ X, const int* __restrict__ row_ptr,
    const int* __restrict__ csr_src, const float* __restrict__ nd,
    const float* __restrict__ bias, void* __restrict__ Y, int n) {
  constexpr int LPN = 64 / EPI;    // lanes per edge-row
  constexpr int HPL = D / LPN;     // halves per lane
  static_assert(HPL >= 2 && HPL <= 8, "bad HPL");
  const int v = (blockIdx.x * blockDim.x + threadIdx.x) >> 6;
  const int lane = threadIdx.x & 63;
  if (v >= n) return;
  const int sub = lane / LPN;
  const int fl = lane % LPN;
  const int off = fl * HPL;
  const __half* __restrict__ Xo = X + off;

  float acc[HPL] = {};
  if (sub == 0) raw_acc<HPL>(acc, graw<HPL>(Xo + (size_t)v * D));   // self term

  const int beg = row_ptr[v];
  const int end = row_ptr[v + 1];
#pragma unroll 2
  for (int e = beg; e < end; e += EPI) {
    int ei = e + sub;
    if (ei < end) {
      int u = csr_src[ei];
      raw_acc<HPL>(acc, graw<HPL>(Xo + (size_t)u * D));
    }
  }

  // combine sub-edge partial sums (butterfly over the sub dimension)
#pragma unroll
  for (int o = LPN; o < 64; o <<= 1)
#pragma unroll
    for (int i = 0; i < HPL; ++i) acc[i] += __shfl_xor(acc[i], o);

  if (sub != 0) return;
  const float sc = nd[v];
  float o[HPL];
#pragma unroll
  for (int i = 0; i < HPL; ++i) {
    o[i] = sc * acc[i];
    if (BIAS) o[i] += bias[off + i];
  }

  if constexpr (OHALF) {
    __half* yp = reinterpret_cast<__half*>(Y) + (size_t)v * D + off;
    if constexpr (HPL == 8) {
      union { struct { __half2 a, b, c, d; } h; uint4 u; } pk;
      pk.h.a = __floats2half2_rn(o[0], o[1]);
      pk.h.b = __floats2half2_rn(o[2], o[3]);
      pk.h.c = __floats2half2_rn(o[4], o[5]);
      pk.h.d = __floats2half2_rn(o[6], o[7]);
      *reinterpret_cast<uint4*>(yp) = pk.u;
    } else if constexpr (HPL == 4) {
      union { struct { __half2 a, b; } h; uint2 u; } pk;
      pk.h.a = __floats2half2_rn(o[0], o[1]);
      pk.h.b = __floats2half2_rn(o[2], o[3]);
      *reinterpret_cast<uint2*>(yp) = pk.u;
    } else {
      *reinterpret_cast<__half2*>(yp) = __floats2half2_rn(o[0], o[1]);
    }
  } else {
    float* yp = reinterpret_cast<float*>(Y) + (size_t)v * D + off;
    if constexpr (HPL == 8) {
      *reinterpret_cast<float4*>(yp) = make_float4(o[0], o[1], o[2], o[3]);
      *reinterpret_cast<float4*>(yp + 4) = make_float4(o[4], o[5], o[6], o[7]);
    } else if constexpr (HPL == 4) {
      *reinterpret_cast<float4*>(yp) = make_float4(o[0], o[1], o[2], o[3]);
    } else {
      *reinterpret_cast<float2*>(yp) = make_float2(o[0], o[1]);
    }
  }
}

// ---------------- pure-fp16 MFMA GEMM ----------------
template <int K, int NOUT, int BM, int WM, int WN, int MF, int NF,
          bool RELU, bool BIAS, bool NSOUT, bool OHALF>
__global__ __launch_bounds__(256) void k_gemm_h(
    const __half* __restrict__ A, const __half* __restrict__ Wt,
    const float* __restrict__ bias, const float* __restrict__ ns,
    void* __restrict__ C, int M) {
  constexpr int BN = WN * NF * 16;
  static_assert(BM == WM * MF * 16, "BM mismatch");
  static_assert(BN == NOUT, "BN must equal NOUT");
  constexpr int LDP = 40;  // 80B row stride -> bank stride 20 -> <=2-way (free), 16B aligned

  __shared__ __half As[BM][LDP];
  __shared__ __half Ws[BN][LDP];

  const int tid = threadIdx.x;
  const int bm = blockIdx.x * BM;
  const int lane = tid & 63;
  const int wave = tid >> 6;
  const int wmi = wave / WN;
  const int wni = wave % WN;
  const int rl = lane & 15;
  const int kg = lane >> 4;       // 0..3
  const int kb = kg * 8;

  f32x4 acc[MF][NF];
#pragma unroll
  for (int m = 0; m < MF; ++m)
#pragma unroll
    for (int n = 0; n < NF; ++n) acc[m][n] = (f32x4){0.f, 0.f, 0.f, 0.f};

  for (int kk = 0; kk < K; kk += 32) {
#pragma unroll
    for (int s0 = 0; s0 < BM * 4; s0 += 256) {
      int s = s0 + tid;
      int r = s >> 2, c8 = (s & 3) << 3;
      int grow = bm + r;
      ushort8v v = (ushort8v){0, 0, 0, 0, 0, 0, 0, 0};
      if (grow < M)
        v = *reinterpret_cast<const ushort8v*>(A + (size_t)grow * K + kk + c8);
      *reinterpret_cast<ushort8v*>(&As[r][c8]) = v;
    }
#pragma unroll
    for (int s0 = 0; s0 < BN * 4; s0 += 256) {
      int s = s0 + tid;
      int nn = s >> 2, k8 = (s & 3) << 3;
      *reinterpret_cast<ushort8v*>(&Ws[nn][k8]) =
          *reinterpret_cast<const ushort8v*>(Wt + (size_t)nn * K + kk + k8);
    }
    __syncthreads();

    f16x8 af[MF], bf[NF];
#pragma unroll
    for (int m = 0; m < MF; ++m) {
      const int r = wmi * MF * 16 + m * 16 + rl;
      af[m] = *reinterpret_cast<const f16x8*>(&As[r][kb]);
    }
#pragma unroll
    for (int n = 0; n < NF; ++n) {
      const int c = wni * NF * 16 + n * 16 + rl;
      bf[n] = *reinterpret_cast<const f16x8*>(&Ws[c][kb]);
    }
#pragma unroll
    for (int m = 0; m < MF; ++m)
#pragma unroll
      for (int n = 0; n < NF; ++n)
        acc[m][n] = __builtin_amdgcn_mfma_f32_16x16x32_f16(af[m], bf[n], acc[m][n], 0, 0, 0);
    __syncthreads();
  }

#pragma unroll
  for (int m = 0; m < MF; ++m) {
#pragma unroll
    for (int n = 0; n < NF; ++n) {
      const int col = wni * NF * 16 + n * 16 + rl;
      const float bb = BIAS ? bias[col] : 0.f;
      const int rowbase = bm + wmi * MF * 16 + m * 16 + kg * 4;
#pragma unroll
      for (int i = 0; i < 4; ++i) {
        int grow = rowbase + i;
        if (grow < M) {
          float val = acc[m][n][i] + bb;
          if (RELU) val = fmaxf(val, 0.f);
          if (NSOUT) val *= ns[grow];
          if constexpr (OHALF)
            reinterpret_cast<__half*>(C)[(size_t)grow * NOUT + col] = __float2half_rn(val);
          else
            reinterpret_cast<float*>(C)[(size_t)grow * NOUT + col] = val;
        }
      }
    }
  }
}

// ---------------- launch ----------------
extern "C" void kernel_launch(void* const* d_in, const int* in_sizes, int n_in,
                              void* d_out, int out_size, void* d_ws, size_t ws_size,
                              hipStream_t stream) {
  const float* feats = (const float*)d_in[0];
  const float* W1 = (const float*)d_in[1];
  const float* b1 = (const float*)d_in[2];
  const float* W2 = (const float*)d_in[3];
  const float* b2 = (const float*)d_in[4];
  const float* W3 = (const float*)d_in[5];
  const float* b3 = (const float*)d_in[6];
  const int* src = (const int*)d_in[7];
  const int* dst = (const int*)d_in[8];
  float* out = (float*)d_out;
  const int N = NODES;
  const int E = in_sizes[7];
  const int NB = (N + 255) / 256;          // scan blocks (196 <= 256)

  char* ws = (char*)d_ws;
  size_t off = 0;
  auto alloc = [&](size_t bytes) -> void* {
    void* p = ws + off;
    off += (bytes + 255) & ~(size_t)255;
    return p;
  };
  __half* w0h = (__half*)alloc((size_t)N * 256 * sizeof(__half));
  __half* w1r = (__half*)alloc((size_t)N * 256 * sizeof(__half));
  __half* w2r = (__half*)alloc((size_t)N * 256 * sizeof(__half));
  int* deg_in = (int*)alloc((size_t)N * sizeof(int));
  float* ns = (float*)alloc((size_t)N * sizeof(float));
  float* nd = (float*)alloc((size_t)N * sizeof(float));
  int* row_ptr = (int*)alloc((size_t)(N + 1) * sizeof(int));
  int* csr_src = (int*)alloc((size_t)E * sizeof(int));
  int* psum = (int*)alloc((size_t)NB * sizeof(int));
  unsigned* p_out = (unsigned*)alloc((size_t)SLICES * NPACK * sizeof(unsigned));
  unsigned* p_in = (unsigned*)alloc((size_t)SLICES * NPACK * sizeof(unsigned));
  unsigned* base_in = (unsigned*)alloc((size_t)SLICES * NPACK * sizeof(unsigned));
  __half* wt1 = (__half*)alloc((size_t)F_IN * F_H1 * sizeof(__half));
  __half* wt2 = (__half*)alloc((size_t)F_H1 * F_H2 * sizeof(__half));
  __half* wt3 = (__half*)alloc((size_t)F_H2 * F_OUT * sizeof(__half));
  (void)ws_size; (void)n_in; (void)out_size;

  // ---- weight transpose -> fp16 (tiny) ----
  hipLaunchKernelGGL(k_wprep_h, dim3((F_IN * F_H1 + 255) / 256), dim3(256), 0, stream,
                     W1, wt1, F_IN, F_H1);
  hipLaunchKernelGGL(k_wprep_h, dim3((F_H1 * F_H2 + 255) / 256), dim3(256), 0, stream,
                     W2, wt2, F_H1, F_H2);
  hipLaunchKernelGGL(k_wprep_h, dim3((F_H2 * F_OUT + 255) / 256), dim3(256), 0, stream,
                     W3, wt3, F_H2, F_OUT);

  // ---- graph preprocessing (no global atomics) ----
  hipLaunchKernelGGL(k_hist, dim3(SLICES * 2), dim3(512), 0, stream,
                     src, dst, p_out, p_in, E);
  hipLaunchKernelGGL(k_degnorm, dim3((NPACK + 255) / 256), dim3(256), 0, stream,
                     p_out, p_in, base_in, deg_in, ns, nd);
  hipLaunchKernelGGL(k_scan1, dim3(NB), dim3(256), 0, stream, deg_in, psum, N);
  hipLaunchKernelGGL(k_scan2, dim3(1), dim3(256), 0, stream, psum, NB);
  hipLaunchKernelGGL(k_scan3, dim3(NB), dim3(256), 0, stream, deg_in, psum, row_ptr, N);
  hipLaunchKernelGGL(k_scatter2, dim3(SLICES * 2), dim3(512), 0, stream,
                     src, dst, row_ptr, base_in, csr_src, E);

  // ---- prescale feats by ns -> fp16 ----
  hipLaunchKernelGGL(k_prescale_h, dim3((N * 32 + 255) / 256), dim3(256), 0, stream,
                     feats, ns, w2r, N * 32);

  auto grid_w = [](int waves) { return dim3((waves + 3) / 4); };  // 4 waves/block

  // ---- layer 1: SpMM(d=128, EPI=4) -> fp16; GEMM 128->256 (+b1, relu, *ns) -> fp16
  hipLaunchKernelGGL((k_spmm_h<128, 4, false, true>), grid_w(N), dim3(256), 0, stream,
                     w2r, row_ptr, csr_src, nd, nullptr, w1r, N);
  hipLaunchKernelGGL((k_gemm_h<128, 256, 64, 1, 4, 4, 4, true, true, true, true>),
                     dim3((N + 63) / 64), dim3(256), 0, stream,
                     w1r, wt1, b1, ns, w2r, N);

  // ---- layer 2: SpMM(d=256, EPI=2) -> fp16; GEMM 256->256 (+b2, relu, *ns) -> fp16
  hipLaunchKernelGGL((k_spmm_h<256, 2, false, true>), grid_w(N), dim3(256), 0, stream,
                     w2r, row_ptr, csr_src, nd, nullptr, w0h, N);
  hipLaunchKernelGGL((k_gemm_h<256, 256, 64, 1, 4, 4, 4, true, true, true, true>),
                     dim3((N + 63) / 64), dim3(256), 0, stream,
                     w0h, wt2, b2, ns, w1r, N);

  // ---- layer 3: GEMM 256->64 (no act) -> fp16; SpMM(d=64, EPI=4) +b3 -> out f32
  hipLaunchKernelGGL((k_gemm_h<256, 64, 128, 4, 1, 2, 4, false, false, false, true>),
                     dim3((N + 127) / 128), dim3(256), 0, stream,
                     w1r, wt3, nullptr, nullptr, w2r, N);
  hipLaunchKernelGGL((k_spmm_h<64, 4, true, false>), grid_w(N), dim3(256), 0, stream,
                     w2r, row_ptr, csr_src, nd, b3, out, N);
}